// Round 6
// baseline (354.053 us; speedup 1.0000x reference)
//
#include <hip/hip_runtime.h>

// VQ-VAE vector quantizer, MI355X (gfx950).
// z: [B=32, C=256, H=32, W=32] fp32; emb: [K=1024, C=256] fp32.
// Outputs (flat f32): z_q [B,C,H,W] (8388608) | loss (1) | idx-as-float (32768).
//
// score = ||e||^2 - 2 z.e via ONE bf16 MFMA (A = bf16(-2z), B = bf16(e)),
// register-double-buffered B prefetch across 32 (kt,ks) chunks.
// Pixels with top-2 gap < MARGIN are recomputed bit-exactly vs numpy fp32
// (pairwise sums + SSE einsum replica) by npfix_kernel, which also patches
// z_q rows and per-pixel loss. loss_fin sums ploss deterministically.

#define BB     32
#define CDIM   256
#define HW     1024
#define KK     1024
#define NPIX   (BB * HW)

#define MARGIN  2.5e-4f
#define LISTCAP 16384
#define FPX     8

typedef __attribute__((ext_vector_type(8))) short bf16x8;
typedef __attribute__((ext_vector_type(4))) float f32x4;

__device__ __forceinline__ unsigned short bf16_rn(float f) {
    unsigned int u = __float_as_uint(f);
    unsigned int r = u + 0x7fffu + ((u >> 16) & 1u);   // RNE
    return (unsigned short)(r >> 16);
}
__device__ __forceinline__ f32x4 mfma16(bf16x8 a, bf16x8 b, f32x4 c) {
    return __builtin_amdgcn_mfma_f32_16x16x32_bf16(a, b, c, 0, 0, 0);
}

// ---------------------------------------------------- numpy pairwise replica
__device__ __forceinline__ float pw128_sq(const float* a) {
#pragma clang fp contract(off)
    float4 u = *(const float4*)(a);
    float4 v = *(const float4*)(a + 4);
    float r0 = u.x * u.x, r1 = u.y * u.y, r2 = u.z * u.z, r3 = u.w * u.w;
    float r4 = v.x * v.x, r5 = v.y * v.y, r6 = v.z * v.z, r7 = v.w * v.w;
    for (int i = 8; i < 128; i += 8) {
        float4 p = *(const float4*)(a + i);
        float4 q = *(const float4*)(a + i + 4);
        float s0 = p.x * p.x; r0 = r0 + s0;
        float s1 = p.y * p.y; r1 = r1 + s1;
        float s2 = p.z * p.z; r2 = r2 + s2;
        float s3 = p.w * p.w; r3 = r3 + s3;
        float s4 = q.x * q.x; r4 = r4 + s4;
        float s5 = q.y * q.y; r5 = r5 + s5;
        float s6 = q.z * q.z; r6 = r6 + s6;
        float s7 = q.w * q.w; r7 = r7 + s7;
    }
    return ((r0 + r1) + (r2 + r3)) + ((r4 + r5) + (r6 + r7));
}

// ------------------------------------- e-norms (numpy-bit-exact) + cnt reset
__global__ void enorm_np_kernel(const float* __restrict__ emb,
                                float* __restrict__ enorm,
                                int* __restrict__ cnt) {
    if (blockIdx.x == 0 && threadIdx.x == 0) cnt[0] = 0;
    const int k = blockIdx.x * blockDim.x + threadIdx.x;
    const float* e = emb + (size_t)k * CDIM;
    float s;
    {
#pragma clang fp contract(off)
        float L = pw128_sq(e);
        float R = pw128_sq(e + 128);
        s = L + R;
    }
    enorm[k] = s;
}

// ----------------------------------------------------------- emb -> bf16 hi
__global__ void embcvt_kernel(const float* __restrict__ emb,
                              unsigned short* __restrict__ ehi) {
    const int i = blockIdx.x * 256 + threadIdx.x;   // 65536 float4s
    const float4 v = ((const float4*)emb)[i];
    ushort4 hv;
    hv.x = bf16_rn(v.x); hv.y = bf16_rn(v.y);
    hv.z = bf16_rn(v.z); hv.w = bf16_rn(v.w);
    ((ushort4*)ehi)[i] = hv;
}

// ---------------------------------------------------- B-fragment prefetcher
__device__ __forceinline__ void loadB(bf16x8 (&B)[4], const unsigned short* eb,
                                      int kt, int ks) {
#pragma unroll
    for (int ni = 0; ni < 4; ++ni)
        B[ni] = *(const bf16x8*)(eb + kt * 65536 + ni * 4096 + ks * 32);
}

// --------------------------------------------- MFMA argmin + fused z_q/loss
// block: 64 pixels x all 1024 codes; 4 waves; wave wn covers codes
// kt*256 + wn*64 + ni*16 + (lane&15), kt = 0..3.
__global__ __launch_bounds__(256, 3)
void argmin_fused_kernel(const float* __restrict__ z,
                         const unsigned short* __restrict__ ehi,
                         const float* __restrict__ emb,
                         const float* __restrict__ enorm,
                         float* __restrict__ idx_f,
                         int* __restrict__ cnt, int* __restrict__ list,
                         float* __restrict__ zq, float* __restrict__ ploss) {
    __shared__ unsigned short zhi[64][272];   // byte stride 544 -> 2-way banks on frags
    __shared__ float mrgB[4][64];
    __shared__ float mrgB2[4][64];
    __shared__ int   mrgI[4][64];
    __shared__ float plss[4][64];
    __shared__ int   idxs[64];

    const int t   = threadIdx.x;
    const int px0 = blockIdx.x * 64;
    const int b   = px0 >> 10;
    const int hw0 = px0 & 1023;

    // stage: read z [c][hw] coalesced (non-temporal), bf16(-2z) -> [px][c]
#pragma unroll
    for (int it = 0; it < 16; ++it) {
        const int c     = it * 16 + (t >> 4);
        const int chunk = t & 15;
        const f32x4 v = __builtin_nontemporal_load(
            (const f32x4*)(z + ((size_t)(b * 256 + c)) * 1024 + hw0 + chunk * 4));
#pragma unroll
        for (int i = 0; i < 4; ++i) {
            const int ie = (i + chunk) & 3;        // rotate store order
            const int px = chunk * 4 + ie;
            zhi[px][c] = bf16_rn(-2.0f * v[ie]);
        }
    }
    __syncthreads();

    const int wn   = t >> 6;
    const int lane = t & 63;
    const int li   = lane & 15;
    const int lk   = lane >> 4;
    const unsigned short* eb = ehi + ((size_t)(wn * 64 + li)) * 256 + lk * 8;

    float sb[4][4], sb2[4][4];
    int   si[4][4];
#pragma unroll
    for (int mi = 0; mi < 4; ++mi)
#pragma unroll
        for (int r = 0; r < 4; ++r) { sb[mi][r] = 3.4e38f; sb2[mi][r] = 3.4e38f; si[mi][r] = 0; }

    bf16x8 Bev[4], Bod[4];
    loadB(Bev, eb, 0, 0);

#pragma unroll
    for (int kt = 0; kt < 4; ++kt) {
        f32x4 acc[4][4];
#pragma unroll
        for (int ni = 0; ni < 4; ++ni) {
            const float en = enorm[kt * 256 + wn * 64 + ni * 16 + li];
#pragma unroll
            for (int mi = 0; mi < 4; ++mi) {
                acc[mi][ni][0] = en; acc[mi][ni][1] = en;
                acc[mi][ni][2] = en; acc[mi][ni][3] = en;
            }
        }
#pragma unroll
        for (int ks = 0; ks < 8; ++ks) {
            const int cidx = kt * 8 + ks;
            const int nkt  = (ks == 7) ? kt + 1 : kt;
            const int nks  = (ks + 1) & 7;
            if ((cidx & 1) == 0) {
                if (cidx < 31) loadB(Bod, eb, nkt, nks);   // prefetch next chunk
#pragma unroll
                for (int mi = 0; mi < 4; ++mi) {
                    const bf16x8 Ah = *(const bf16x8*)&zhi[mi * 16 + li][lk * 8 + ks * 32];
#pragma unroll
                    for (int ni = 0; ni < 4; ++ni)
                        acc[mi][ni] = mfma16(Ah, Bev[ni], acc[mi][ni]);
                }
            } else {
                if (cidx < 31) loadB(Bev, eb, nkt, nks);
#pragma unroll
                for (int mi = 0; mi < 4; ++mi) {
                    const bf16x8 Ah = *(const bf16x8*)&zhi[mi * 16 + li][lk * 8 + ks * 32];
#pragma unroll
                    for (int ni = 0; ni < 4; ++ni)
                        acc[mi][ni] = mfma16(Ah, Bod[ni], acc[mi][ni]);
                }
            }
        }
        // merge this kt's scores into running top-2 (k ascending)
#pragma unroll
        for (int mi = 0; mi < 4; ++mi)
#pragma unroll
            for (int ni = 0; ni < 4; ++ni) {
                const int k = kt * 256 + wn * 64 + ni * 16 + li;
#pragma unroll
                for (int r = 0; r < 4; ++r) {
                    const float v = acc[mi][ni][r];
                    if (v < sb[mi][r]) {
                        sb2[mi][r] = sb[mi][r]; sb[mi][r] = v; si[mi][r] = k;
                    } else {
                        sb2[mi][r] = fminf(sb2[mi][r], v);
                    }
                }
            }
    }

    // cross-lane reduce over the 16 li lanes (same lk share the same pixels)
#pragma unroll
    for (int m = 1; m < 16; m <<= 1) {
#pragma unroll
        for (int mi = 0; mi < 4; ++mi)
#pragma unroll
            for (int r = 0; r < 4; ++r) {
                const float ob  = __shfl_xor(sb[mi][r], m, 64);
                const float ob2 = __shfl_xor(sb2[mi][r], m, 64);
                const int   oi  = __shfl_xor(si[mi][r], m, 64);
                const bool take = (ob < sb[mi][r]) || (ob == sb[mi][r] && oi < si[mi][r]);
                const float mx  = take ? sb[mi][r] : ob;     // loser's best
                sb2[mi][r] = fminf(fminf(sb2[mi][r], ob2), mx);
                if (take) { sb[mi][r] = ob; si[mi][r] = oi; }
            }
    }
    if (li == 0) {
#pragma unroll
        for (int mi = 0; mi < 4; ++mi)
#pragma unroll
            for (int r = 0; r < 4; ++r) {
                const int pl = mi * 16 + lk * 4 + r;
                mrgB [wn][pl] = sb[mi][r];
                mrgB2[wn][pl] = sb2[mi][r];
                mrgI [wn][pl] = si[mi][r];
            }
    }
    __syncthreads();
    if (t < 64) {
        float bv = mrgB[0][t], bv2 = mrgB2[0][t];
        int   bi = mrgI[0][t];
#pragma unroll
        for (int w = 1; w < 4; ++w) {
            const float ob  = mrgB [w][t];
            const float ob2 = mrgB2[w][t];
            const int   oi  = mrgI [w][t];
            const bool take = (ob < bv) || (ob == bv && oi < bi);
            const float mx  = take ? bv : ob;
            bv2 = fminf(fminf(bv2, ob2), mx);
            if (take) { bv = ob; bi = oi; }
        }
        const int n = px0 + t;
        idxs[t]  = bi;
        idx_f[n] = (float)bi;
        if (bv2 - bv < MARGIN) {
            const int slot = atomicAdd(cnt, 1);
            if (slot < LISTCAP) list[slot] = n;
        }
    }
    __syncthreads();

    // ---- fused epilogue: z_q gather + per-pixel loss
    {
        const int px = t & 63;
        const int cr = t >> 6;                 // wave owns c-range cr*64..+63
        const int bi = idxs[px];
        const float* erow = emb + (size_t)bi * CDIM + cr * 64;
        const float* zrow = z  + ((size_t)(b * 256 + cr * 64)) * 1024 + hw0 + px;
        float*       qrow = zq + ((size_t)(b * 256 + cr * 64)) * 1024 + hw0 + px;
        float ls = 0.f;
#pragma unroll
        for (int jq = 0; jq < 16; ++jq) {
            const f32x4 e4 = *(const f32x4*)(erow + jq * 4);
#pragma unroll
            for (int i2 = 0; i2 < 4; ++i2) {
                const size_t off = (size_t)(jq * 4 + i2) * 1024;
                const float zv = __builtin_nontemporal_load(zrow + off);
                const float w  = e4[i2];
                __builtin_nontemporal_store(w, qrow + off);
                const float d = w - zv;
                ls = fmaf(d, d, ls);
            }
        }
        plss[cr][px] = ls;
    }
    __syncthreads();
    if (t < 64)
        ploss[px0 + t] = (plss[0][t] + plss[1][t]) + (plss[2][t] + plss[3][t]);
}

// --------------------------- numpy-fp32 bit-exact recompute for flagged px
__global__ __launch_bounds__(256)
void npfix_kernel(const float* __restrict__ z, const float* __restrict__ emb,
                  const float* __restrict__ enorm_np,
                  const int* __restrict__ cnt, const int* __restrict__ list,
                  float* __restrict__ idx_f, float* __restrict__ zq,
                  float* __restrict__ ploss) {
    __shared__ __align__(16) float zrow[FPX][CDIM];
    __shared__ float znp[FPX];
    __shared__ int   pxn[FPX];
    __shared__ float redv[256];
    __shared__ int   redk[256];
    const int t = threadIdx.x;
    const int nflag = min(cnt[0], LISTCAP);

    for (int base = blockIdx.x * FPX; base < nflag; base += gridDim.x * FPX) {
        const int npx = min(FPX, nflag - base);
        if (t < FPX) pxn[t] = list[base + (t < npx ? t : npx - 1)];
        __syncthreads();
#pragma unroll
        for (int px = 0; px < FPX; ++px) {
            const int n = pxn[px];
            zrow[px][t] = z[(size_t)(n >> 10) * (CDIM * HW) + (size_t)t * HW + (n & 1023)];
        }
        __syncthreads();
        if (t < FPX) {
#pragma clang fp contract(off)
            float L = pw128_sq(&zrow[t][0]);
            float R = pw128_sq(&zrow[t][128]);
            znp[t] = L + R;
        }
        __syncthreads();

        float bv[FPX]; int bki[FPX];
#pragma unroll
        for (int px = 0; px < FPX; ++px) { bv[px] = 3.4e38f; bki[px] = 0; }

        for (int kj = 0; kj < 4; ++kj) {
            const int k = t + kj * 256;
            const float* er = emb + (size_t)k * CDIM;
            float l[FPX][4];
#pragma unroll
            for (int px = 0; px < FPX; ++px)
#pragma unroll
                for (int j = 0; j < 4; ++j) l[px][j] = 0.f;
            {
#pragma clang fp contract(off)
                for (int m = 0; m < 64; ++m) {
                    const float4 e4 = *(const float4*)(er + 4 * m);
#pragma unroll
                    for (int px = 0; px < FPX; ++px) {
                        const float4 z4 = *(const float4*)(&zrow[px][4 * m]);
                        float p0 = e4.x * z4.x; l[px][0] = l[px][0] + p0;
                        float p1 = e4.y * z4.y; l[px][1] = l[px][1] + p1;
                        float p2 = e4.z * z4.z; l[px][2] = l[px][2] + p2;
                        float p3 = e4.w * z4.w; l[px][3] = l[px][3] + p3;
                    }
                }
#pragma unroll
                for (int px = 0; px < FPX; ++px) {
                    float dot = (l[px][0] + l[px][1]) + (l[px][2] + l[px][3]);
                    float S   = znp[px] + enorm_np[k];
                    float tw  = 2.0f * dot;
                    float d   = S - tw;
                    if (d < bv[px]) { bv[px] = d; bki[px] = k; }
                }
            }
        }
        for (int px = 0; px < FPX; ++px) {
            __syncthreads();
            redv[t] = bv[px]; redk[t] = bki[px];
            __syncthreads();
            for (int s = 128; s > 0; s >>= 1) {
                if (t < s) {
                    const float v2 = redv[t + s];
                    const int   k2 = redk[t + s];
                    if (v2 < redv[t] || (v2 == redv[t] && k2 < redk[t])) {
                        redv[t] = v2; redk[t] = k2;
                    }
                }
                __syncthreads();
            }
            if (px < npx) {                       // block-uniform
                const int n   = pxn[px];
                const int nbi = redk[0];
                if (t == 0) idx_f[n] = (float)nbi;
                // patch z_q row + per-pixel loss
                const float w = emb[(size_t)nbi * CDIM + t];
                zq[((size_t)((n >> 10) * 256 + t)) * 1024 + (n & 1023)] = w;
                const float d = w - zrow[px][t];
                __syncthreads();
                redv[t] = d * d;
                __syncthreads();
                for (int s2 = 128; s2 > 0; s2 >>= 1) {
                    if (t < s2) redv[t] += redv[t + s2];
                    __syncthreads();
                }
                if (t == 0) ploss[n] = redv[0];
            }
        }
        __syncthreads();
    }
}

// ------------------------------------------------- deterministic loss reduce
__global__ void loss_fin_kernel(const float* __restrict__ ploss,
                                float* __restrict__ loss_out) {
    __shared__ double red[256];
    const int t = threadIdx.x;   // 256 threads
    double s = 0.0;
    for (int i = 0; i < NPIX / 256; ++i) s += (double)ploss[t + i * 256];
    red[t] = s;
    __syncthreads();
    for (int st = 128; st > 0; st >>= 1) {
        if (t < st) red[t] += red[t + st];
        __syncthreads();
    }
    if (t == 0)
        loss_out[0] = (float)(0.25 * red[0] / (double)((size_t)BB * CDIM * HW));
}

// ---------------------------------------------------------------- launch
extern "C" void kernel_launch(void* const* d_in, const int* in_sizes, int n_in,
                              void* d_out, int out_size, void* d_ws, size_t ws_size,
                              hipStream_t stream) {
    const float* z   = (const float*)d_in[0];
    const float* emb = (const float*)d_in[1];

    float* out  = (float*)d_out;
    float* zq   = out;
    float* loss = out + (size_t)BB * CDIM * HW;
    float* idxf = loss + 1;

    char* ws = (char*)d_ws;
    float*          enorm = (float*)(ws);                    // 4096 B
    int*            cnt   = (int*)(ws + 4096);               // 256 B
    int*            list  = (int*)(ws + 8192);               // 65536 B
    unsigned short* ehi   = (unsigned short*)(ws + 73728);   // 524288 B
    float*          ploss = (float*)(ws + 598016);           // 131072 B

    embcvt_kernel<<<256, 256, 0, stream>>>(emb, ehi);
    enorm_np_kernel<<<KK / 256, 256, 0, stream>>>(emb, enorm, cnt);

    argmin_fused_kernel<<<NPIX / 64, 256, 0, stream>>>(z, ehi, emb, enorm,
                                                       idxf, cnt, list, zq, ploss);
    npfix_kernel<<<512, 256, 0, stream>>>(z, emb, enorm, cnt, list, idxf, zq, ploss);
    loss_fin_kernel<<<1, 256, 0, stream>>>(ploss, loss);
}

// Round 7
// 244.696 us; speedup vs baseline: 1.4469x; 1.4469x over previous
//
#include <hip/hip_runtime.h>

// VQ-VAE vector quantizer, MI355X (gfx950).
// z: [B=32, C=256, H=32, W=32] fp32; emb: [K=1024, C=256] fp32.
// Outputs (flat f32): z_q [B,C,H,W] (8388608) | loss (1) | idx-as-float (32768).
//
// score = ||e||^2 - 2 z.e via ONE bf16 MFMA (A = bf16(-2z), B = bf16(e)).
// B (bf16 emb) is PRE-SWIZZLED to MFMA-fragment-linear layout
// [k16][ks][lk][li][cj] so each wave B-load is one contiguous 1KB block
// (R6 lesson: the [k][c] layout made every B load a 64-line gather).
// Register double-buffered B prefetch across the 32 (kt,ks) chunks.
// Pixels with top-2 gap < MARGIN recomputed bit-exactly vs numpy fp32
// (pairwise sums + SSE einsum replica) by npfix_kernel.
// z_q + loss in a separate float4-vectorized kernel (R6 lesson: fused
// scalar-nt-store epilogue caused 23x HBM write amplification).

#define BB     32
#define CDIM   256
#define HW     1024
#define KK     1024
#define NPIX   (BB * HW)

#define MARGIN  2.5e-4f
#define LISTCAP 16384
#define FPX     8

typedef __attribute__((ext_vector_type(8))) short bf16x8;
typedef __attribute__((ext_vector_type(4))) float f32x4;

__device__ __forceinline__ unsigned short bf16_rn(float f) {
    unsigned int u = __float_as_uint(f);
    unsigned int r = u + 0x7fffu + ((u >> 16) & 1u);   // RNE
    return (unsigned short)(r >> 16);
}
__device__ __forceinline__ f32x4 mfma16(bf16x8 a, bf16x8 b, f32x4 c) {
    return __builtin_amdgcn_mfma_f32_16x16x32_bf16(a, b, c, 0, 0, 0);
}

// ---------------------------------------------------- numpy pairwise replica
__device__ __forceinline__ float pw128_sq(const float* a) {
#pragma clang fp contract(off)
    float4 u = *(const float4*)(a);
    float4 v = *(const float4*)(a + 4);
    float r0 = u.x * u.x, r1 = u.y * u.y, r2 = u.z * u.z, r3 = u.w * u.w;
    float r4 = v.x * v.x, r5 = v.y * v.y, r6 = v.z * v.z, r7 = v.w * v.w;
    for (int i = 8; i < 128; i += 8) {
        float4 p = *(const float4*)(a + i);
        float4 q = *(const float4*)(a + i + 4);
        float s0 = p.x * p.x; r0 = r0 + s0;
        float s1 = p.y * p.y; r1 = r1 + s1;
        float s2 = p.z * p.z; r2 = r2 + s2;
        float s3 = p.w * p.w; r3 = r3 + s3;
        float s4 = q.x * q.x; r4 = r4 + s4;
        float s5 = q.y * q.y; r5 = r5 + s5;
        float s6 = q.z * q.z; r6 = r6 + s6;
        float s7 = q.w * q.w; r7 = r7 + s7;
    }
    return ((r0 + r1) + (r2 + r3)) + ((r4 + r5) + (r6 + r7));
}

// ------------------------------------- e-norms (numpy-bit-exact) + cnt reset
__global__ void enorm_np_kernel(const float* __restrict__ emb,
                                float* __restrict__ enorm,
                                int* __restrict__ cnt) {
    if (blockIdx.x == 0 && threadIdx.x == 0) cnt[0] = 0;
    const int k = blockIdx.x * blockDim.x + threadIdx.x;
    const float* e = emb + (size_t)k * CDIM;
    float s;
    {
#pragma clang fp contract(off)
        float L = pw128_sq(e);
        float R = pw128_sq(e + 128);
        s = L + R;
    }
    enorm[k] = s;
}

// ------------------------- emb -> bf16, swizzled to MFMA-fragment order
// out[k16][ks][lk][li][cj]: k16=k>>4, li=k&15, ks=c>>5, lk=(c>>3)&3, cj=c&7
// -> flat shorts: k16*4096 + ks*512 + lk*128 + li*8 + cj
__global__ void embcvt_kernel(const float* __restrict__ emb,
                              unsigned short* __restrict__ ehi) {
    const int i = blockIdx.x * 256 + threadIdx.x;   // 65536 float4s
    const int k = i >> 6;
    const int c = (i & 63) * 4;
    const float4 v = ((const float4*)emb)[i];
    ushort4 hv;
    hv.x = bf16_rn(v.x); hv.y = bf16_rn(v.y);
    hv.z = bf16_rn(v.z); hv.w = bf16_rn(v.w);
    const int off = (k >> 4) * 4096 + (c >> 5) * 512 + ((c >> 3) & 3) * 128
                  + (k & 15) * 8 + (c & 7);
    *(ushort4*)(ehi + off) = hv;
}

// ---------------------------------------------------- B-fragment prefetcher
// eb = ehi + wn*4*4096 + lane*8  (lane-contiguous 1KB per fragment)
__device__ __forceinline__ void loadB(bf16x8 (&B)[4], const unsigned short* eb,
                                      int kt, int ks) {
#pragma unroll
    for (int ni = 0; ni < 4; ++ni)
        B[ni] = *(const bf16x8*)(eb + kt * 65536 + ni * 4096 + ks * 512);
}

// ---------------------------------------------------------- MFMA argmin
// block: 64 pixels x all 1024 codes; 4 waves; wave wn covers codes
// kt*256 + wn*64 + ni*16 + (lane&15), kt = 0..3.
__global__ __launch_bounds__(256, 2)
void argmin_mfma_kernel(const float* __restrict__ z,
                        const unsigned short* __restrict__ ehi,
                        const float* __restrict__ enorm,
                        int* __restrict__ idx_i, float* __restrict__ idx_f,
                        int* __restrict__ cnt, int* __restrict__ list) {
    __shared__ unsigned short zhi[64][272];
    __shared__ float mrgB[4][64];
    __shared__ float mrgB2[4][64];
    __shared__ int   mrgI[4][64];

    const int t   = threadIdx.x;
    const int px0 = blockIdx.x * 64;
    const int b   = px0 >> 10;
    const int hw0 = px0 & 1023;

    // stage: read z [c][hw] coalesced (non-temporal), bf16(-2z) -> [px][c]
#pragma unroll
    for (int it = 0; it < 16; ++it) {
        const int c     = it * 16 + (t >> 4);
        const int chunk = t & 15;
        const f32x4 v = __builtin_nontemporal_load(
            (const f32x4*)(z + ((size_t)(b * 256 + c)) * 1024 + hw0 + chunk * 4));
#pragma unroll
        for (int i = 0; i < 4; ++i) {
            const int ie = (i + chunk) & 3;        // rotate store order
            const int px = chunk * 4 + ie;
            zhi[px][c] = bf16_rn(-2.0f * v[ie]);
        }
    }
    __syncthreads();

    const int wn   = t >> 6;
    const int lane = t & 63;
    const int li   = lane & 15;
    const int lk   = lane >> 4;
    const unsigned short* eb = ehi + wn * 4 * 4096 + lane * 8;

    float sb[4][4], sb2[4][4];
    int   si[4][4];
#pragma unroll
    for (int mi = 0; mi < 4; ++mi)
#pragma unroll
        for (int r = 0; r < 4; ++r) { sb[mi][r] = 3.4e38f; sb2[mi][r] = 3.4e38f; si[mi][r] = 0; }

    bf16x8 Bev[4], Bod[4];
    loadB(Bev, eb, 0, 0);

#pragma unroll
    for (int kt = 0; kt < 4; ++kt) {
        f32x4 acc[4][4];
#pragma unroll
        for (int ni = 0; ni < 4; ++ni) {
            const float en = enorm[kt * 256 + wn * 64 + ni * 16 + li];
#pragma unroll
            for (int mi = 0; mi < 4; ++mi) {
                acc[mi][ni][0] = en; acc[mi][ni][1] = en;
                acc[mi][ni][2] = en; acc[mi][ni][3] = en;
            }
        }
#pragma unroll
        for (int ks = 0; ks < 8; ++ks) {
            const int cidx = kt * 8 + ks;
            const int nkt  = (ks == 7) ? kt + 1 : kt;
            const int nks  = (ks + 1) & 7;
            if ((cidx & 1) == 0) {
                if (cidx < 31) loadB(Bod, eb, nkt, nks);   // prefetch next chunk
#pragma unroll
                for (int mi = 0; mi < 4; ++mi) {
                    const bf16x8 Ah = *(const bf16x8*)&zhi[mi * 16 + li][lk * 8 + ks * 32];
#pragma unroll
                    for (int ni = 0; ni < 4; ++ni)
                        acc[mi][ni] = mfma16(Ah, Bev[ni], acc[mi][ni]);
                }
            } else {
                if (cidx < 31) loadB(Bev, eb, nkt, nks);
#pragma unroll
                for (int mi = 0; mi < 4; ++mi) {
                    const bf16x8 Ah = *(const bf16x8*)&zhi[mi * 16 + li][lk * 8 + ks * 32];
#pragma unroll
                    for (int ni = 0; ni < 4; ++ni)
                        acc[mi][ni] = mfma16(Ah, Bod[ni], acc[mi][ni]);
                }
            }
        }
        // merge this kt's scores into running top-2 (k ascending)
#pragma unroll
        for (int mi = 0; mi < 4; ++mi)
#pragma unroll
            for (int ni = 0; ni < 4; ++ni) {
                const int k = kt * 256 + wn * 64 + ni * 16 + li;
#pragma unroll
                for (int r = 0; r < 4; ++r) {
                    const float v = acc[mi][ni][r];
                    if (v < sb[mi][r]) {
                        sb2[mi][r] = sb[mi][r]; sb[mi][r] = v; si[mi][r] = k;
                    } else {
                        sb2[mi][r] = fminf(sb2[mi][r], v);
                    }
                }
            }
    }

    // cross-lane reduce over the 16 li lanes (same lk share the same pixels)
#pragma unroll
    for (int m = 1; m < 16; m <<= 1) {
#pragma unroll
        for (int mi = 0; mi < 4; ++mi)
#pragma unroll
            for (int r = 0; r < 4; ++r) {
                const float ob  = __shfl_xor(sb[mi][r], m, 64);
                const float ob2 = __shfl_xor(sb2[mi][r], m, 64);
                const int   oi  = __shfl_xor(si[mi][r], m, 64);
                const bool take = (ob < sb[mi][r]) || (ob == sb[mi][r] && oi < si[mi][r]);
                const float mx  = take ? sb[mi][r] : ob;     // loser's best
                sb2[mi][r] = fminf(fminf(sb2[mi][r], ob2), mx);
                if (take) { sb[mi][r] = ob; si[mi][r] = oi; }
            }
    }
    if (li == 0) {
#pragma unroll
        for (int mi = 0; mi < 4; ++mi)
#pragma unroll
            for (int r = 0; r < 4; ++r) {
                const int pl = mi * 16 + lk * 4 + r;
                mrgB [wn][pl] = sb[mi][r];
                mrgB2[wn][pl] = sb2[mi][r];
                mrgI [wn][pl] = si[mi][r];
            }
    }
    __syncthreads();
    if (t < 64) {
        float bv = mrgB[0][t], bv2 = mrgB2[0][t];
        int   bi = mrgI[0][t];
#pragma unroll
        for (int w = 1; w < 4; ++w) {
            const float ob  = mrgB [w][t];
            const float ob2 = mrgB2[w][t];
            const int   oi  = mrgI [w][t];
            const bool take = (ob < bv) || (ob == bv && oi < bi);
            const float mx  = take ? bv : ob;
            bv2 = fminf(fminf(bv2, ob2), mx);
            if (take) { bv = ob; bi = oi; }
        }
        const int n = px0 + t;
        idx_i[n] = bi;
        idx_f[n] = (float)bi;
        if (bv2 - bv < MARGIN) {
            const int slot = atomicAdd(cnt, 1);
            if (slot < LISTCAP) list[slot] = n;
        }
    }
}

// --------------------------- numpy-fp32 bit-exact recompute for flagged px
__global__ __launch_bounds__(256)
void npfix_kernel(const float* __restrict__ z, const float* __restrict__ emb,
                  const float* __restrict__ enorm_np,
                  const int* __restrict__ cnt, const int* __restrict__ list,
                  int* __restrict__ idx_i, float* __restrict__ idx_f) {
    __shared__ __align__(16) float zrow[FPX][CDIM];
    __shared__ float znp[FPX];
    __shared__ int   pxn[FPX];
    __shared__ float redv[256];
    __shared__ int   redk[256];
    const int t = threadIdx.x;
    const int nflag = min(cnt[0], LISTCAP);

    for (int base = blockIdx.x * FPX; base < nflag; base += gridDim.x * FPX) {
        const int npx = min(FPX, nflag - base);
        if (t < FPX) pxn[t] = list[base + (t < npx ? t : npx - 1)];
        __syncthreads();
#pragma unroll
        for (int px = 0; px < FPX; ++px) {
            const int n = pxn[px];
            zrow[px][t] = z[(size_t)(n >> 10) * (CDIM * HW) + (size_t)t * HW + (n & 1023)];
        }
        __syncthreads();
        if (t < FPX) {
#pragma clang fp contract(off)
            float L = pw128_sq(&zrow[t][0]);
            float R = pw128_sq(&zrow[t][128]);
            znp[t] = L + R;
        }
        __syncthreads();

        float bv[FPX]; int bki[FPX];
#pragma unroll
        for (int px = 0; px < FPX; ++px) { bv[px] = 3.4e38f; bki[px] = 0; }

        for (int kj = 0; kj < 4; ++kj) {
            const int k = t + kj * 256;
            const float* er = emb + (size_t)k * CDIM;
            float l[FPX][4];
#pragma unroll
            for (int px = 0; px < FPX; ++px)
#pragma unroll
                for (int j = 0; j < 4; ++j) l[px][j] = 0.f;
            {
#pragma clang fp contract(off)
                for (int m = 0; m < 64; ++m) {
                    const float4 e4 = *(const float4*)(er + 4 * m);
#pragma unroll
                    for (int px = 0; px < FPX; ++px) {
                        const float4 z4 = *(const float4*)(&zrow[px][4 * m]);
                        float p0 = e4.x * z4.x; l[px][0] = l[px][0] + p0;
                        float p1 = e4.y * z4.y; l[px][1] = l[px][1] + p1;
                        float p2 = e4.z * z4.z; l[px][2] = l[px][2] + p2;
                        float p3 = e4.w * z4.w; l[px][3] = l[px][3] + p3;
                    }
                }
#pragma unroll
                for (int px = 0; px < FPX; ++px) {
                    float dot = (l[px][0] + l[px][1]) + (l[px][2] + l[px][3]);
                    float S   = znp[px] + enorm_np[k];
                    float tw  = 2.0f * dot;
                    float d   = S - tw;
                    if (d < bv[px]) { bv[px] = d; bki[px] = k; }
                }
            }
        }
        for (int px = 0; px < FPX; ++px) {
            __syncthreads();
            redv[t] = bv[px]; redk[t] = bki[px];
            __syncthreads();
            for (int s = 128; s > 0; s >>= 1) {
                if (t < s) {
                    const float v2 = redv[t + s];
                    const int   k2 = redk[t + s];
                    if (v2 < redv[t] || (v2 == redv[t] && k2 < redk[t])) {
                        redv[t] = v2; redk[t] = k2;
                    }
                }
                __syncthreads();
            }
            if (t == 0 && px < npx) {
                const int n = pxn[px];
                idx_i[n] = redk[0];
                idx_f[n] = (float)redk[0];
            }
        }
        __syncthreads();
    }
}

// ---------------------------------------------------------------- z_q + loss
__global__ __launch_bounds__(256)
void zq_loss_kernel(const float* __restrict__ z, const float* __restrict__ emb,
                    const int* __restrict__ idx_i, float* __restrict__ zq,
                    double* __restrict__ lpart) {
    const int blk = blockIdx.x;
    const int b   = blk >> 3;
    const int cch = blk & 7;
    const int t   = threadIdx.x;
    const int hw  = t * 4;
    const int n0  = b * HW + hw;

    const float* e0 = emb + (size_t)idx_i[n0 + 0] * CDIM + cch * 32;
    const float* e1 = emb + (size_t)idx_i[n0 + 1] * CDIM + cch * 32;
    const float* e2 = emb + (size_t)idx_i[n0 + 2] * CDIM + cch * 32;
    const float* e3 = emb + (size_t)idx_i[n0 + 3] * CDIM + cch * 32;

    const size_t base = ((size_t)b * CDIM + cch * 32) * HW + hw;
    const float* zb = z + base;
    float*       ob = zq + base;

    float ls = 0.f;
#pragma unroll
    for (int c4 = 0; c4 < 8; ++c4) {
        const float4 a0 = *(const float4*)(e0 + 4 * c4);
        const float4 a1 = *(const float4*)(e1 + 4 * c4);
        const float4 a2 = *(const float4*)(e2 + 4 * c4);
        const float4 a3 = *(const float4*)(e3 + 4 * c4);
        const float av0[4] = {a0.x, a0.y, a0.z, a0.w};
        const float av1[4] = {a1.x, a1.y, a1.z, a1.w};
        const float av2[4] = {a2.x, a2.y, a2.z, a2.w};
        const float av3[4] = {a3.x, a3.y, a3.z, a3.w};
#pragma unroll
        for (int cj = 0; cj < 4; ++cj) {
            const size_t off = (size_t)(c4 * 4 + cj) * HW;
            const f32x4 zv = __builtin_nontemporal_load((const f32x4*)(zb + off));
            f32x4 o;
            o[0] = av0[cj]; o[1] = av1[cj]; o[2] = av2[cj]; o[3] = av3[cj];
            __builtin_nontemporal_store(o, (f32x4*)(ob + off));
            const float d0 = o[0] - zv[0], d1 = o[1] - zv[1];
            const float d2 = o[2] - zv[2], d3 = o[3] - zv[3];
            ls += d0 * d0 + d1 * d1 + d2 * d2 + d3 * d3;
        }
    }

    __shared__ float red[256];
    red[t] = ls;
    __syncthreads();
    if (t < 128) red[t] += red[t + 128];
    __syncthreads();
    if (t < 64) {
        float s = red[t] + red[t + 64];
#pragma unroll
        for (int off = 32; off > 0; off >>= 1) s += __shfl_down(s, off, 64);
        if (t == 0) lpart[blk] = (double)s;
    }
}

__global__ void loss_fin_kernel(const double* __restrict__ lpart,
                                float* __restrict__ loss_out) {
    const int t = threadIdx.x;
    double s = 0.0;
#pragma unroll
    for (int i = 0; i < 4; ++i) s += lpart[t * 4 + i];
#pragma unroll
    for (int off = 32; off > 0; off >>= 1) s += __shfl_down(s, off, 64);
    if (t == 0)
        loss_out[0] = (float)(0.25 * s / (double)((size_t)BB * CDIM * HW));
}

// ---------------------------------------------------------------- launch
extern "C" void kernel_launch(void* const* d_in, const int* in_sizes, int n_in,
                              void* d_out, int out_size, void* d_ws, size_t ws_size,
                              hipStream_t stream) {
    const float* z   = (const float*)d_in[0];
    const float* emb = (const float*)d_in[1];

    float* out  = (float*)d_out;
    float* zq   = out;
    float* loss = out + (size_t)BB * CDIM * HW;
    float* idxf = loss + 1;

    char* ws = (char*)d_ws;
    int*            idx_i = (int*)(ws);                      // 131072 B
    float*          enorm = (float*)(ws + 131072);           // 4096 B
    double*         lpart = (double*)(ws + 135168);          // 2048 B
    int*            cnt   = (int*)(ws + 137216);             // 256 B
    int*            list  = (int*)(ws + 137472);             // 65536 B
    unsigned short* ehi   = (unsigned short*)(ws + 203008);  // 524288 B

    embcvt_kernel<<<256, 256, 0, stream>>>(emb, ehi);
    enorm_np_kernel<<<KK / 256, 256, 0, stream>>>(emb, enorm, cnt);

    argmin_mfma_kernel<<<NPIX / 64, 256, 0, stream>>>(z, ehi, enorm,
                                                      idx_i, idxf, cnt, list);
    npfix_kernel<<<512, 256, 0, stream>>>(z, emb, enorm, cnt, list, idx_i, idxf);

    zq_loss_kernel<<<BB * 8, 256, 0, stream>>>(z, emb, idx_i, zq, lpart);
    loss_fin_kernel<<<1, 64, 0, stream>>>(lpart, loss);
}

// Round 8
// 235.039 us; speedup vs baseline: 1.5064x; 1.0411x over previous
//
#include <hip/hip_runtime.h>

// VQ-VAE vector quantizer, MI355X (gfx950).
// z: [B=32, C=256, H=32, W=32] fp32; emb: [K=1024, C=256] fp32.
// Outputs (flat f32): z_q [B,C,H,W] (8388608) | loss (1) | idx-as-float (32768).
//
// score = ||e||^2 - 2 z.e via ONE bf16 MFMA (A = bf16(-2z), B = bf16(e)).
// B pre-swizzled to MFMA-fragment-linear layout [k16][ks][lane][cj].
// R8: waves split by PIXELS (16 px/wave, all codes) so all 4 waves issue
// IDENTICAL B loads (L1-shared, phase-locked by per-kt barrier) and top-2
// state is 12 regs (no spills — R7 lesson: 410MB of scratch spill traffic).
// Pixels with top-2 gap < MARGIN recomputed bit-exactly vs numpy fp32
// (pairwise sums + SSE einsum replica) by npfix_kernel.

#define BB     32
#define CDIM   256
#define HW     1024
#define KK     1024
#define NPIX   (BB * HW)

#define MARGIN  2.5e-4f
#define LISTCAP 16384
#define FPX     8

typedef __attribute__((ext_vector_type(8))) short bf16x8;
typedef __attribute__((ext_vector_type(4))) float f32x4;

__device__ __forceinline__ unsigned short bf16_rn(float f) {
    unsigned int u = __float_as_uint(f);
    unsigned int r = u + 0x7fffu + ((u >> 16) & 1u);   // RNE
    return (unsigned short)(r >> 16);
}
__device__ __forceinline__ f32x4 mfma16(bf16x8 a, bf16x8 b, f32x4 c) {
    return __builtin_amdgcn_mfma_f32_16x16x32_bf16(a, b, c, 0, 0, 0);
}

// ---------------------------------------------------- numpy pairwise replica
__device__ __forceinline__ float pw128_sq(const float* a) {
#pragma clang fp contract(off)
    float4 u = *(const float4*)(a);
    float4 v = *(const float4*)(a + 4);
    float r0 = u.x * u.x, r1 = u.y * u.y, r2 = u.z * u.z, r3 = u.w * u.w;
    float r4 = v.x * v.x, r5 = v.y * v.y, r6 = v.z * v.z, r7 = v.w * v.w;
    for (int i = 8; i < 128; i += 8) {
        float4 p = *(const float4*)(a + i);
        float4 q = *(const float4*)(a + i + 4);
        float s0 = p.x * p.x; r0 = r0 + s0;
        float s1 = p.y * p.y; r1 = r1 + s1;
        float s2 = p.z * p.z; r2 = r2 + s2;
        float s3 = p.w * p.w; r3 = r3 + s3;
        float s4 = q.x * q.x; r4 = r4 + s4;
        float s5 = q.y * q.y; r5 = r5 + s5;
        float s6 = q.z * q.z; r6 = r6 + s6;
        float s7 = q.w * q.w; r7 = r7 + s7;
    }
    return ((r0 + r1) + (r2 + r3)) + ((r4 + r5) + (r6 + r7));
}

// ------------------------------------- e-norms (numpy-bit-exact) + cnt reset
__global__ void enorm_np_kernel(const float* __restrict__ emb,
                                float* __restrict__ enorm,
                                int* __restrict__ cnt) {
    if (blockIdx.x == 0 && threadIdx.x == 0) cnt[0] = 0;
    const int k = blockIdx.x * blockDim.x + threadIdx.x;
    const float* e = emb + (size_t)k * CDIM;
    float s;
    {
#pragma clang fp contract(off)
        float L = pw128_sq(e);
        float R = pw128_sq(e + 128);
        s = L + R;
    }
    enorm[k] = s;
}

// ------------------------- emb -> bf16, swizzled to MFMA-fragment order
// flat shorts: (k>>4)*4096 + (c>>5)*512 + ((c>>3)&3)*128 + (k&15)*8 + (c&7)
__global__ void embcvt_kernel(const float* __restrict__ emb,
                              unsigned short* __restrict__ ehi) {
    const int i = blockIdx.x * 256 + threadIdx.x;   // 65536 float4s
    const int k = i >> 6;
    const int c = (i & 63) * 4;
    const float4 v = ((const float4*)emb)[i];
    ushort4 hv;
    hv.x = bf16_rn(v.x); hv.y = bf16_rn(v.y);
    hv.z = bf16_rn(v.z); hv.w = bf16_rn(v.w);
    const int off = (k >> 4) * 4096 + (c >> 5) * 512 + ((c >> 3) & 3) * 128
                  + (k & 15) * 8 + (c & 7);
    *(ushort4*)(ehi + off) = hv;
}

// ---------------------------------------------------- B-batch loader
// q = ks*4 + nb; loads ni = nb*4+j for j=0..3 at k-slice ks.
__device__ __forceinline__ void loadB4(bf16x8 (&B)[4], const unsigned short* ek,
                                       int q) {
    const int base = (q >> 2) * 512 + (q & 3) * 4 * 4096;
#pragma unroll
    for (int j = 0; j < 4; ++j)
        B[j] = *(const bf16x8*)(ek + base + j * 4096);
}

// ---------------------------------------------------------- MFMA argmin
// block: 64 pixels x all 1024 codes; 4 waves; wave wn owns pixels
// wn*16..wn*16+15; all waves sweep the SAME code stream (L1-shared B).
__global__ __launch_bounds__(256, 3)
void argmin_mfma_kernel(const float* __restrict__ z,
                        const unsigned short* __restrict__ ehi,
                        const float* __restrict__ enorm,
                        int* __restrict__ idx_i, float* __restrict__ idx_f,
                        int* __restrict__ cnt, int* __restrict__ list) {
    __shared__ unsigned short zhi[64][272];

    const int t   = threadIdx.x;
    const int px0 = blockIdx.x * 64;
    const int b   = px0 >> 10;
    const int hw0 = px0 & 1023;

    // stage: read z [c][hw] coalesced (non-temporal), bf16(-2z) -> [px][c]
#pragma unroll
    for (int it = 0; it < 16; ++it) {
        const int c     = it * 16 + (t >> 4);
        const int chunk = t & 15;
        const f32x4 v = __builtin_nontemporal_load(
            (const f32x4*)(z + ((size_t)(b * 256 + c)) * 1024 + hw0 + chunk * 4));
#pragma unroll
        for (int i = 0; i < 4; ++i) {
            const int ie = (i + chunk) & 3;        // rotate store order
            const int px = chunk * 4 + ie;
            zhi[px][c] = bf16_rn(-2.0f * v[ie]);
        }
    }
    __syncthreads();

    const int wn   = t >> 6;
    const int lane = t & 63;
    const int li   = lane & 15;
    const int lk   = lane >> 4;

    float sb[4], sb2[4];
    int   si[4];
#pragma unroll
    for (int r = 0; r < 4; ++r) { sb[r] = 3.4e38f; sb2[r] = 3.4e38f; si[r] = 0; }

    for (int kt = 0; kt < 4; ++kt) {
        __syncthreads();                       // phase-lock waves on B stream
        const unsigned short* ek = ehi + kt * 65536 + lane * 8;

        f32x4 acc[16];
#pragma unroll
        for (int ni = 0; ni < 16; ++ni) {
            const float en = enorm[kt * 256 + ni * 16 + li];
            acc[ni][0] = en; acc[ni][1] = en; acc[ni][2] = en; acc[ni][3] = en;
        }

        bf16x8 B0[4], B1[4], A;
        loadB4(B0, ek, 0);
#pragma unroll
        for (int q = 0; q < 32; ++q) {
            const int ks = q >> 2;
            const int nb = q & 3;
            if (nb == 0)
                A = *(const bf16x8*)&zhi[wn * 16 + li][lk * 8 + ks * 32];
            if ((q & 1) == 0) {
                if (q < 31) loadB4(B1, ek, q + 1);
#pragma unroll
                for (int j = 0; j < 4; ++j)
                    acc[nb * 4 + j] = mfma16(A, B0[j], acc[nb * 4 + j]);
            } else {
                if (q < 31) loadB4(B0, ek, q + 1);
#pragma unroll
                for (int j = 0; j < 4; ++j)
                    acc[nb * 4 + j] = mfma16(A, B1[j], acc[nb * 4 + j]);
            }
        }

        // merge this kt's 64 scores/lane into running top-2 (ni ascending)
#pragma unroll
        for (int ni = 0; ni < 16; ++ni) {
            const int k = kt * 256 + ni * 16 + li;
#pragma unroll
            for (int r = 0; r < 4; ++r) {
                const float v = acc[ni][r];
                if (v < sb[r]) {
                    sb2[r] = sb[r]; sb[r] = v; si[r] = k;
                } else {
                    sb2[r] = fminf(sb2[r], v);
                }
            }
        }
    }

    // cross-lane reduce over the 16 li lanes (same lk,r share a pixel)
#pragma unroll
    for (int m = 1; m < 16; m <<= 1) {
#pragma unroll
        for (int r = 0; r < 4; ++r) {
            const float ob  = __shfl_xor(sb[r], m, 64);
            const float ob2 = __shfl_xor(sb2[r], m, 64);
            const int   oi  = __shfl_xor(si[r], m, 64);
            const bool take = (ob < sb[r]) || (ob == sb[r] && oi < si[r]);
            const float mx  = take ? sb[r] : ob;     // loser's best
            sb2[r] = fminf(fminf(sb2[r], ob2), mx);
            if (take) { sb[r] = ob; si[r] = oi; }
        }
    }
    if (li == 0) {
#pragma unroll
        for (int r = 0; r < 4; ++r) {
            const int n = px0 + wn * 16 + lk * 4 + r;
            idx_i[n] = si[r];
            idx_f[n] = (float)si[r];
            if (sb2[r] - sb[r] < MARGIN) {
                const int slot = atomicAdd(cnt, 1);
                if (slot < LISTCAP) list[slot] = n;
            }
        }
    }
}

// --------------------------- numpy-fp32 bit-exact recompute for flagged px
__global__ __launch_bounds__(256)
void npfix_kernel(const float* __restrict__ z, const float* __restrict__ emb,
                  const float* __restrict__ enorm_np,
                  const int* __restrict__ cnt, const int* __restrict__ list,
                  int* __restrict__ idx_i, float* __restrict__ idx_f) {
    __shared__ __align__(16) float zrow[FPX][CDIM];
    __shared__ float znp[FPX];
    __shared__ int   pxn[FPX];
    __shared__ float redv[256];
    __shared__ int   redk[256];
    const int t = threadIdx.x;
    const int nflag = min(cnt[0], LISTCAP);

    for (int base = blockIdx.x * FPX; base < nflag; base += gridDim.x * FPX) {
        const int npx = min(FPX, nflag - base);
        if (t < FPX) pxn[t] = list[base + (t < npx ? t : npx - 1)];
        __syncthreads();
#pragma unroll
        for (int px = 0; px < FPX; ++px) {
            const int n = pxn[px];
            zrow[px][t] = z[(size_t)(n >> 10) * (CDIM * HW) + (size_t)t * HW + (n & 1023)];
        }
        __syncthreads();
        if (t < FPX) {
#pragma clang fp contract(off)
            float L = pw128_sq(&zrow[t][0]);
            float R = pw128_sq(&zrow[t][128]);
            znp[t] = L + R;
        }
        __syncthreads();

        float bv[FPX]; int bki[FPX];
#pragma unroll
        for (int px = 0; px < FPX; ++px) { bv[px] = 3.4e38f; bki[px] = 0; }

        for (int kj = 0; kj < 4; ++kj) {
            const int k = t + kj * 256;
            const float* er = emb + (size_t)k * CDIM;
            float l[FPX][4];
#pragma unroll
            for (int px = 0; px < FPX; ++px)
#pragma unroll
                for (int j = 0; j < 4; ++j) l[px][j] = 0.f;
            {
#pragma clang fp contract(off)
                for (int m = 0; m < 64; ++m) {
                    const float4 e4 = *(const float4*)(er + 4 * m);
#pragma unroll
                    for (int px = 0; px < FPX; ++px) {
                        const float4 z4 = *(const float4*)(&zrow[px][4 * m]);
                        float p0 = e4.x * z4.x; l[px][0] = l[px][0] + p0;
                        float p1 = e4.y * z4.y; l[px][1] = l[px][1] + p1;
                        float p2 = e4.z * z4.z; l[px][2] = l[px][2] + p2;
                        float p3 = e4.w * z4.w; l[px][3] = l[px][3] + p3;
                    }
                }
#pragma unroll
                for (int px = 0; px < FPX; ++px) {
                    float dot = (l[px][0] + l[px][1]) + (l[px][2] + l[px][3]);
                    float S   = znp[px] + enorm_np[k];
                    float tw  = 2.0f * dot;
                    float d   = S - tw;
                    if (d < bv[px]) { bv[px] = d; bki[px] = k; }
                }
            }
        }
        for (int px = 0; px < FPX; ++px) {
            __syncthreads();
            redv[t] = bv[px]; redk[t] = bki[px];
            __syncthreads();
            for (int s = 128; s > 0; s >>= 1) {
                if (t < s) {
                    const float v2 = redv[t + s];
                    const int   k2 = redk[t + s];
                    if (v2 < redv[t] || (v2 == redv[t] && k2 < redk[t])) {
                        redv[t] = v2; redk[t] = k2;
                    }
                }
                __syncthreads();
            }
            if (t == 0 && px < npx) {
                const int n = pxn[px];
                idx_i[n] = redk[0];
                idx_f[n] = (float)redk[0];
            }
        }
        __syncthreads();
    }
}

// ---------------------------------------------------------------- z_q + loss
__global__ __launch_bounds__(256)
void zq_loss_kernel(const float* __restrict__ z, const float* __restrict__ emb,
                    const int* __restrict__ idx_i, float* __restrict__ zq,
                    double* __restrict__ lpart) {
    const int blk = blockIdx.x;
    const int b   = blk >> 3;
    const int cch = blk & 7;
    const int t   = threadIdx.x;
    const int hw  = t * 4;
    const int n0  = b * HW + hw;

    const float* e0 = emb + (size_t)idx_i[n0 + 0] * CDIM + cch * 32;
    const float* e1 = emb + (size_t)idx_i[n0 + 1] * CDIM + cch * 32;
    const float* e2 = emb + (size_t)idx_i[n0 + 2] * CDIM + cch * 32;
    const float* e3 = emb + (size_t)idx_i[n0 + 3] * CDIM + cch * 32;

    const size_t base = ((size_t)b * CDIM + cch * 32) * HW + hw;
    const float* zb = z + base;
    float*       ob = zq + base;

    float ls = 0.f;
#pragma unroll
    for (int c4 = 0; c4 < 8; ++c4) {
        const float4 a0 = *(const float4*)(e0 + 4 * c4);
        const float4 a1 = *(const float4*)(e1 + 4 * c4);
        const float4 a2 = *(const float4*)(e2 + 4 * c4);
        const float4 a3 = *(const float4*)(e3 + 4 * c4);
        const float av0[4] = {a0.x, a0.y, a0.z, a0.w};
        const float av1[4] = {a1.x, a1.y, a1.z, a1.w};
        const float av2[4] = {a2.x, a2.y, a2.z, a2.w};
        const float av3[4] = {a3.x, a3.y, a3.z, a3.w};
#pragma unroll
        for (int cj = 0; cj < 4; ++cj) {
            const size_t off = (size_t)(c4 * 4 + cj) * HW;
            const f32x4 zv = __builtin_nontemporal_load((const f32x4*)(zb + off));
            f32x4 o;
            o[0] = av0[cj]; o[1] = av1[cj]; o[2] = av2[cj]; o[3] = av3[cj];
            __builtin_nontemporal_store(o, (f32x4*)(ob + off));
            const float d0 = o[0] - zv[0], d1 = o[1] - zv[1];
            const float d2 = o[2] - zv[2], d3 = o[3] - zv[3];
            ls += d0 * d0 + d1 * d1 + d2 * d2 + d3 * d3;
        }
    }

    __shared__ float red[256];
    red[t] = ls;
    __syncthreads();
    if (t < 128) red[t] += red[t + 128];
    __syncthreads();
    if (t < 64) {
        float s = red[t] + red[t + 64];
#pragma unroll
        for (int off = 32; off > 0; off >>= 1) s += __shfl_down(s, off, 64);
        if (t == 0) lpart[blk] = (double)s;
    }
}

__global__ void loss_fin_kernel(const double* __restrict__ lpart,
                                float* __restrict__ loss_out) {
    const int t = threadIdx.x;
    double s = 0.0;
#pragma unroll
    for (int i = 0; i < 4; ++i) s += lpart[t * 4 + i];
#pragma unroll
    for (int off = 32; off > 0; off >>= 1) s += __shfl_down(s, off, 64);
    if (t == 0)
        loss_out[0] = (float)(0.25 * s / (double)((size_t)BB * CDIM * HW));
}

// ---------------------------------------------------------------- launch
extern "C" void kernel_launch(void* const* d_in, const int* in_sizes, int n_in,
                              void* d_out, int out_size, void* d_ws, size_t ws_size,
                              hipStream_t stream) {
    const float* z   = (const float*)d_in[0];
    const float* emb = (const float*)d_in[1];

    float* out  = (float*)d_out;
    float* zq   = out;
    float* loss = out + (size_t)BB * CDIM * HW;
    float* idxf = loss + 1;

    char* ws = (char*)d_ws;
    int*            idx_i = (int*)(ws);                      // 131072 B
    float*          enorm = (float*)(ws + 131072);           // 4096 B
    double*         lpart = (double*)(ws + 135168);          // 2048 B
    int*            cnt   = (int*)(ws + 137216);             // 256 B
    int*            list  = (int*)(ws + 137472);             // 65536 B
    unsigned short* ehi   = (unsigned short*)(ws + 203008);  // 524288 B

    embcvt_kernel<<<256, 256, 0, stream>>>(emb, ehi);
    enorm_np_kernel<<<KK / 256, 256, 0, stream>>>(emb, enorm, cnt);

    argmin_mfma_kernel<<<NPIX / 64, 256, 0, stream>>>(z, ehi, enorm,
                                                      idx_i, idxf, cnt, list);
    npfix_kernel<<<512, 256, 0, stream>>>(z, emb, enorm, cnt, list, idx_i, idxf);

    zq_loss_kernel<<<BB * 8, 256, 0, stream>>>(z, emb, idx_i, zq, lpart);
    loss_fin_kernel<<<1, 64, 0, stream>>>(lpart, loss);
}

// Round 9
// 158.022 us; speedup vs baseline: 2.2405x; 1.4874x over previous
//
#include <hip/hip_runtime.h>

// VQ-VAE vector quantizer, MI355X (gfx950).
// z: [B=32, C=256, H=32, W=32] fp32; emb: [K=1024, C=256] fp32.
// Outputs (flat f32): z_q [B,C,H,W] (8388608) | loss (1) | idx-as-float (32768).
//
// score = ||e||^2 - 2 z.e via ONE bf16 MFMA (A = bf16(-2z), B = bf16(e)).
// R9: canonical LDS-staged GEMM loop — B chunks (256 codes x 32 c = 16 KB,
// fragment-linear) DMA'd via global_load_lds into a double buffer; all 4
// waves (pixel-split, 16 px each) consume the same chunk via ds_read
// broadcast. R8 lesson: per-q register prefetch (depth-1) left the kernel
// latency-bound at 4% MfmaUtil.
// Pixels with top-2 gap < MARGIN recomputed bit-exactly vs numpy fp32
// (pairwise sums + SSE einsum replica) by npfix_kernel.

#define BB     32
#define CDIM   256
#define HW     1024
#define KK     1024
#define NPIX   (BB * HW)

#define MARGIN  2.5e-4f
#define LISTCAP 16384
#define FPX     8

typedef __attribute__((ext_vector_type(8))) short bf16x8;
typedef __attribute__((ext_vector_type(4))) float f32x4;

__device__ __forceinline__ unsigned short bf16_rn(float f) {
    unsigned int u = __float_as_uint(f);
    unsigned int r = u + 0x7fffu + ((u >> 16) & 1u);   // RNE
    return (unsigned short)(r >> 16);
}
__device__ __forceinline__ f32x4 mfma16(bf16x8 a, bf16x8 b, f32x4 c) {
    return __builtin_amdgcn_mfma_f32_16x16x32_bf16(a, b, c, 0, 0, 0);
}

// ---------------------------------------------------- numpy pairwise replica
__device__ __forceinline__ float pw128_sq(const float* a) {
#pragma clang fp contract(off)
    float4 u = *(const float4*)(a);
    float4 v = *(const float4*)(a + 4);
    float r0 = u.x * u.x, r1 = u.y * u.y, r2 = u.z * u.z, r3 = u.w * u.w;
    float r4 = v.x * v.x, r5 = v.y * v.y, r6 = v.z * v.z, r7 = v.w * v.w;
    for (int i = 8; i < 128; i += 8) {
        float4 p = *(const float4*)(a + i);
        float4 q = *(const float4*)(a + i + 4);
        float s0 = p.x * p.x; r0 = r0 + s0;
        float s1 = p.y * p.y; r1 = r1 + s1;
        float s2 = p.z * p.z; r2 = r2 + s2;
        float s3 = p.w * p.w; r3 = r3 + s3;
        float s4 = q.x * q.x; r4 = r4 + s4;
        float s5 = q.y * q.y; r5 = r5 + s5;
        float s6 = q.z * q.z; r6 = r6 + s6;
        float s7 = q.w * q.w; r7 = r7 + s7;
    }
    return ((r0 + r1) + (r2 + r3)) + ((r4 + r5) + (r6 + r7));
}

// ------------------------------------- e-norms (numpy-bit-exact) + cnt reset
__global__ void enorm_np_kernel(const float* __restrict__ emb,
                                float* __restrict__ enorm,
                                int* __restrict__ cnt) {
    if (blockIdx.x == 0 && threadIdx.x == 0) cnt[0] = 0;
    const int k = blockIdx.x * blockDim.x + threadIdx.x;
    const float* e = emb + (size_t)k * CDIM;
    float s;
    {
#pragma clang fp contract(off)
        float L = pw128_sq(e);
        float R = pw128_sq(e + 128);
        s = L + R;
    }
    enorm[k] = s;
}

// ------------- emb -> bf16, swizzled to CHUNK-CONTIGUOUS fragment order
// chunk (kt,ks) = 256 codes x 32 c = 16 KB, fragments linear inside:
// off = ((kt*8+ks)*16 + k16)*512 + (lk*16+li)*8 + cj
//   kt=k>>8, k16=(k>>4)&15, li=k&15, ks=c>>5, lk=(c>>3)&3, cj=c&7
__global__ void embcvt_kernel(const float* __restrict__ emb,
                              unsigned short* __restrict__ ehi) {
    const int i = blockIdx.x * 256 + threadIdx.x;   // 65536 float4s
    const int k = i >> 6;
    const int c = (i & 63) * 4;
    const float4 v = ((const float4*)emb)[i];
    ushort4 hv;
    hv.x = bf16_rn(v.x); hv.y = bf16_rn(v.y);
    hv.z = bf16_rn(v.z); hv.w = bf16_rn(v.w);
    const int kt = k >> 8, k16 = (k >> 4) & 15, li = k & 15;
    const int ks = c >> 5, lk = (c >> 3) & 3, cj = c & 7;
    const int off = (((kt * 8 + ks) * 16 + k16) << 9) + (lk * 16 + li) * 8 + cj;
    *(ushort4*)(ehi + off) = hv;
}

// ---------------------------------------------------------- MFMA argmin
// block: 64 pixels x all 1024 codes; 4 waves; wave wn owns pixels
// wn*16..wn*16+15. B chunks staged to LDS via global_load_lds, dbuf.
__global__ __launch_bounds__(256, 2)
void argmin_mfma_kernel(const float* __restrict__ z,
                        const unsigned short* __restrict__ ehi,
                        const float* __restrict__ enorm,
                        int* __restrict__ idx_i, float* __restrict__ idx_f,
                        int* __restrict__ cnt, int* __restrict__ list) {
    __shared__ __align__(16) unsigned short zhi[64][272];
    __shared__ __align__(16) unsigned short blds[2][8192];   // 2 x 16 KB

    const int t    = threadIdx.x;
    const int px0  = blockIdx.x * 64;
    const int b    = px0 >> 10;
    const int hw0  = px0 & 1023;
    const int wn   = t >> 6;
    const int lane = t & 63;
    const int li   = lane & 15;
    const int lk   = lane >> 4;

    // stage chunk ch into blds[buf]: 16 KB, wave wn DMAs parts wn*4..wn*4+3
    auto stage = [&](int ch, int buf) {
#pragma unroll
        for (int p = 0; p < 4; ++p) {
            const int part = wn * 4 + p;                    // 1 KB per part
            const unsigned short* gsl = ehi + (size_t)ch * 8192 + part * 512 + lane * 8;
            unsigned short* ldst = &blds[buf][part * 512];
            __builtin_amdgcn_global_load_lds(
                (const __attribute__((address_space(1))) unsigned int*)(const void*)gsl,
                (__attribute__((address_space(3))) unsigned int*)(void*)ldst,
                16, 0, 0);
        }
    };

    // stage z: read [c][hw] coalesced (non-temporal), bf16(-2z) -> [px][c]
#pragma unroll
    for (int it = 0; it < 16; ++it) {
        const int c     = it * 16 + (t >> 4);
        const int chunk = t & 15;
        const f32x4 v = __builtin_nontemporal_load(
            (const f32x4*)(z + ((size_t)(b * 256 + c)) * 1024 + hw0 + chunk * 4));
#pragma unroll
        for (int i = 0; i < 4; ++i) {
            const int ie = (i + chunk) & 3;        // rotate store order
            const int px = chunk * 4 + ie;
            zhi[px][c] = bf16_rn(-2.0f * v[ie]);
        }
    }
    stage(0, 0);
    __syncthreads();          // zhi visible + chunk 0 DMA drained

    float sb[4], sb2[4];
    int   si[4];
#pragma unroll
    for (int r = 0; r < 4; ++r) { sb[r] = 3.4e38f; sb2[r] = 3.4e38f; si[r] = 0; }

    f32x4 acc[16];

    for (int ch = 0; ch < 32; ++ch) {        // chunk = kt*8 + ks
        const int kt = ch >> 3;
        const int ks = ch & 7;
        const int buf = ch & 1;

        if (ks == 0) {
#pragma unroll
            for (int ni = 0; ni < 16; ++ni) {
                const float en = enorm[kt * 256 + ni * 16 + li];
                acc[ni][0] = en; acc[ni][1] = en; acc[ni][2] = en; acc[ni][3] = en;
            }
        }

        if (ch < 31) stage(ch + 1, buf ^ 1);   // DMA next chunk

        const bf16x8 A = *(const bf16x8*)&zhi[wn * 16 + li][lk * 8 + ks * 32];
#pragma unroll
        for (int ni = 0; ni < 16; ++ni) {
            const bf16x8 Bf = *(const bf16x8*)&blds[buf][ni * 512 + lane * 8];
            acc[ni] = mfma16(A, Bf, acc[ni]);
        }

        if (ks == 7) {
            // merge this kt's 64 scores/lane into running top-2 (ni ascending)
#pragma unroll
            for (int ni = 0; ni < 16; ++ni) {
                const int k = kt * 256 + ni * 16 + li;
#pragma unroll
                for (int r = 0; r < 4; ++r) {
                    const float v = acc[ni][r];
                    if (v < sb[r]) {
                        sb2[r] = sb[r]; sb[r] = v; si[r] = k;
                    } else {
                        sb2[r] = fminf(sb2[r], v);
                    }
                }
            }
        }
        __syncthreads();      // drains next-chunk DMA + this chunk's ds_reads
    }

    // cross-lane reduce over the 16 li lanes (same lk,r share a pixel)
#pragma unroll
    for (int m = 1; m < 16; m <<= 1) {
#pragma unroll
        for (int r = 0; r < 4; ++r) {
            const float ob  = __shfl_xor(sb[r], m, 64);
            const float ob2 = __shfl_xor(sb2[r], m, 64);
            const int   oi  = __shfl_xor(si[r], m, 64);
            const bool take = (ob < sb[r]) || (ob == sb[r] && oi < si[r]);
            const float mx  = take ? sb[r] : ob;     // loser's best
            sb2[r] = fminf(fminf(sb2[r], ob2), mx);
            if (take) { sb[r] = ob; si[r] = oi; }
        }
    }
    if (li == 0) {
#pragma unroll
        for (int r = 0; r < 4; ++r) {
            const int n = px0 + wn * 16 + lk * 4 + r;
            idx_i[n] = si[r];
            idx_f[n] = (float)si[r];
            if (sb2[r] - sb[r] < MARGIN) {
                const int slot = atomicAdd(cnt, 1);
                if (slot < LISTCAP) list[slot] = n;
            }
        }
    }
}

// --------------------------- numpy-fp32 bit-exact recompute for flagged px
__global__ __launch_bounds__(256)
void npfix_kernel(const float* __restrict__ z, const float* __restrict__ emb,
                  const float* __restrict__ enorm_np,
                  const int* __restrict__ cnt, const int* __restrict__ list,
                  int* __restrict__ idx_i, float* __restrict__ idx_f) {
    __shared__ __align__(16) float zrow[FPX][CDIM];
    __shared__ float znp[FPX];
    __shared__ int   pxn[FPX];
    __shared__ float redv[256];
    __shared__ int   redk[256];
    const int t = threadIdx.x;
    const int nflag = min(cnt[0], LISTCAP);

    for (int base = blockIdx.x * FPX; base < nflag; base += gridDim.x * FPX) {
        const int npx = min(FPX, nflag - base);
        if (t < FPX) pxn[t] = list[base + (t < npx ? t : npx - 1)];
        __syncthreads();
#pragma unroll
        for (int px = 0; px < FPX; ++px) {
            const int n = pxn[px];
            zrow[px][t] = z[(size_t)(n >> 10) * (CDIM * HW) + (size_t)t * HW + (n & 1023)];
        }
        __syncthreads();
        if (t < FPX) {
#pragma clang fp contract(off)
            float L = pw128_sq(&zrow[t][0]);
            float R = pw128_sq(&zrow[t][128]);
            znp[t] = L + R;
        }
        __syncthreads();

        float bv[FPX]; int bki[FPX];
#pragma unroll
        for (int px = 0; px < FPX; ++px) { bv[px] = 3.4e38f; bki[px] = 0; }

        for (int kj = 0; kj < 4; ++kj) {
            const int k = t + kj * 256;
            const float* er = emb + (size_t)k * CDIM;
            float l[FPX][4];
#pragma unroll
            for (int px = 0; px < FPX; ++px)
#pragma unroll
                for (int j = 0; j < 4; ++j) l[px][j] = 0.f;
            {
#pragma clang fp contract(off)
                for (int m = 0; m < 64; ++m) {
                    const float4 e4 = *(const float4*)(er + 4 * m);
#pragma unroll
                    for (int px = 0; px < FPX; ++px) {
                        const float4 z4 = *(const float4*)(&zrow[px][4 * m]);
                        float p0 = e4.x * z4.x; l[px][0] = l[px][0] + p0;
                        float p1 = e4.y * z4.y; l[px][1] = l[px][1] + p1;
                        float p2 = e4.z * z4.z; l[px][2] = l[px][2] + p2;
                        float p3 = e4.w * z4.w; l[px][3] = l[px][3] + p3;
                    }
                }
#pragma unroll
                for (int px = 0; px < FPX; ++px) {
                    float dot = (l[px][0] + l[px][1]) + (l[px][2] + l[px][3]);
                    float S   = znp[px] + enorm_np[k];
                    float tw  = 2.0f * dot;
                    float d   = S - tw;
                    if (d < bv[px]) { bv[px] = d; bki[px] = k; }
                }
            }
        }
        for (int px = 0; px < FPX; ++px) {
            __syncthreads();
            redv[t] = bv[px]; redk[t] = bki[px];
            __syncthreads();
            for (int s = 128; s > 0; s >>= 1) {
                if (t < s) {
                    const float v2 = redv[t + s];
                    const int   k2 = redk[t + s];
                    if (v2 < redv[t] || (v2 == redv[t] && k2 < redk[t])) {
                        redv[t] = v2; redk[t] = k2;
                    }
                }
                __syncthreads();
            }
            if (t == 0 && px < npx) {
                const int n = pxn[px];
                idx_i[n] = redk[0];
                idx_f[n] = (float)redk[0];
            }
        }
        __syncthreads();
    }
}

// ---------------------------------------------------------------- z_q + loss
__global__ __launch_bounds__(256)
void zq_loss_kernel(const float* __restrict__ z, const float* __restrict__ emb,
                    const int* __restrict__ idx_i, float* __restrict__ zq,
                    double* __restrict__ lpart) {
    const int blk = blockIdx.x;
    const int b   = blk >> 3;
    const int cch = blk & 7;
    const int t   = threadIdx.x;
    const int hw  = t * 4;
    const int n0  = b * HW + hw;

    const float* e0 = emb + (size_t)idx_i[n0 + 0] * CDIM + cch * 32;
    const float* e1 = emb + (size_t)idx_i[n0 + 1] * CDIM + cch * 32;
    const float* e2 = emb + (size_t)idx_i[n0 + 2] * CDIM + cch * 32;
    const float* e3 = emb + (size_t)idx_i[n0 + 3] * CDIM + cch * 32;

    const size_t base = ((size_t)b * CDIM + cch * 32) * HW + hw;
    const float* zb = z + base;
    float*       ob = zq + base;

    float ls = 0.f;
#pragma unroll
    for (int c4 = 0; c4 < 8; ++c4) {
        const float4 a0 = *(const float4*)(e0 + 4 * c4);
        const float4 a1 = *(const float4*)(e1 + 4 * c4);
        const float4 a2 = *(const float4*)(e2 + 4 * c4);
        const float4 a3 = *(const float4*)(e3 + 4 * c4);
        const float av0[4] = {a0.x, a0.y, a0.z, a0.w};
        const float av1[4] = {a1.x, a1.y, a1.z, a1.w};
        const float av2[4] = {a2.x, a2.y, a2.z, a2.w};
        const float av3[4] = {a3.x, a3.y, a3.z, a3.w};
#pragma unroll
        for (int cj = 0; cj < 4; ++cj) {
            const size_t off = (size_t)(c4 * 4 + cj) * HW;
            const f32x4 zv = __builtin_nontemporal_load((const f32x4*)(zb + off));
            f32x4 o;
            o[0] = av0[cj]; o[1] = av1[cj]; o[2] = av2[cj]; o[3] = av3[cj];
            __builtin_nontemporal_store(o, (f32x4*)(ob + off));
            const float d0 = o[0] - zv[0], d1 = o[1] - zv[1];
            const float d2 = o[2] - zv[2], d3 = o[3] - zv[3];
            ls += d0 * d0 + d1 * d1 + d2 * d2 + d3 * d3;
        }
    }

    __shared__ float red[256];
    red[t] = ls;
    __syncthreads();
    if (t < 128) red[t] += red[t + 128];
    __syncthreads();
    if (t < 64) {
        float s = red[t] + red[t + 64];
#pragma unroll
        for (int off = 32; off > 0; off >>= 1) s += __shfl_down(s, off, 64);
        if (t == 0) lpart[blk] = (double)s;
    }
}

__global__ void loss_fin_kernel(const double* __restrict__ lpart,
                                float* __restrict__ loss_out) {
    const int t = threadIdx.x;
    double s = 0.0;
#pragma unroll
    for (int i = 0; i < 4; ++i) s += lpart[t * 4 + i];
#pragma unroll
    for (int off = 32; off > 0; off >>= 1) s += __shfl_down(s, off, 64);
    if (t == 0)
        loss_out[0] = (float)(0.25 * s / (double)((size_t)BB * CDIM * HW));
}

// ---------------------------------------------------------------- launch
extern "C" void kernel_launch(void* const* d_in, const int* in_sizes, int n_in,
                              void* d_out, int out_size, void* d_ws, size_t ws_size,
                              hipStream_t stream) {
    const float* z   = (const float*)d_in[0];
    const float* emb = (const float*)d_in[1];

    float* out  = (float*)d_out;
    float* zq   = out;
    float* loss = out + (size_t)BB * CDIM * HW;
    float* idxf = loss + 1;

    char* ws = (char*)d_ws;
    int*            idx_i = (int*)(ws);                      // 131072 B
    float*          enorm = (float*)(ws + 131072);           // 4096 B
    double*         lpart = (double*)(ws + 135168);          // 2048 B
    int*            cnt   = (int*)(ws + 137216);             // 256 B
    int*            list  = (int*)(ws + 137472);             // 65536 B
    unsigned short* ehi   = (unsigned short*)(ws + 203008);  // 524288 B

    embcvt_kernel<<<256, 256, 0, stream>>>(emb, ehi);
    enorm_np_kernel<<<KK / 256, 256, 0, stream>>>(emb, enorm, cnt);

    argmin_mfma_kernel<<<NPIX / 64, 256, 0, stream>>>(z, ehi, enorm,
                                                      idx_i, idxf, cnt, list);
    npfix_kernel<<<512, 256, 0, stream>>>(z, emb, enorm, cnt, list, idx_i, idxf);

    zq_loss_kernel<<<BB * 8, 256, 0, stream>>>(z, emb, idx_i, zq, lpart);
    loss_fin_kernel<<<1, 64, 0, stream>>>(lpart, loss);
}